// Round 11
// baseline (133.357 us; speedup 1.0000x reference)
//
#include <hip/hip_runtime.h>
#include <stdint.h>

// ---------------------------------------------------------------------------
// SelfAttentiveBimodalFusion: MLP(192->16->16) -> Q(8),K(8),V(64) -> full
// N x N attention -> out (N,64).  N = 12288.  fp32 in / fp32 out.
// Validated r5-r10: absmax 9.8e-4 vs thr 2.7e-3.
//
// Ladder: r5 killed atomics; r7 occupancy; r9 DMA staging (no spill);
// r10 shared staging + query-split (k2 ~44 us, now below the harness's own
// 45-us 256-MiB d_ws re-poison fill in the top-5).
// r11: the r10 loop was the m97 2-barrier structure (vmcnt(0)+barrier per
// iter drains the DMA queue).  This version is the AITER-style pipeline:
// 3-deep shared V-tile buffer, raw s_barrier (no compiler drain), manual
// s_waitcnt vmcnt(2) -- tile kt+1's DMAs stay IN FLIGHT across the barrier;
// vmcnt(0) only on the last two iterations.  Numerics byte-identical.
// ---------------------------------------------------------------------------

#define NN 12288

typedef float    f32x16 __attribute__((ext_vector_type(16)));
typedef short    s16x8  __attribute__((ext_vector_type(8)));
typedef unsigned short u16;

#define MFMA_32x32x16_BF16 __builtin_amdgcn_mfma_f32_32x32x16_bf16

// ws layout (bytes)
#define OFF_QB   0u          // N*8*2   = 196608  (bf16, pre-scaled)
#define OFF_KB   196608u     // N*8*2   = 196608  (bf16)
#define OFF_VT   393216u     // 384 tiles * 4608 B = 1769472 (bf16 V, tiled)
#define OFF_PO   2162688u    // S*N*64*2 bf16 O partials; pl follows (S*N*4 fp32)

typedef __attribute__((address_space(3))) void lds_void_t;
typedef const __attribute__((address_space(1))) void gbl_void_t;
__device__ __forceinline__ void gld16(const void* g, void* l) {
    __builtin_amdgcn_global_load_lds((gbl_void_t*)g, (lds_void_t*)l, 16, 0, 0);
}

__device__ __forceinline__ float bf2f(u16 s) {
    union { unsigned int u; float f; } c; c.u = ((unsigned int)s) << 16; return c.f;
}
__device__ __forceinline__ u16 f2bf(float f) {
    union { float f; unsigned int u; } c; c.f = f;
    return (u16)((c.u + 0x8000u) >> 16);
}
__device__ __forceinline__ unsigned int pk2(float a, float b) {
    union { float f; unsigned int u; } ca, cb; ca.f = a; cb.f = b;
    return ((ca.u + 0x8000u) >> 16) | ((cb.u + 0x8000u) & 0xffff0000u);
}
__device__ __forceinline__ unsigned int pkbf(float a, float b) {
#if __has_builtin(__builtin_amdgcn_cvt_pk_bf16_f32)
    auto r = __builtin_amdgcn_cvt_pk_bf16_f32(a, b);
    union { decltype(r) v; unsigned int u; } c; c.v = r; return c.u;
#else
    return pk2(a, b);
#endif
}
__device__ __forceinline__ void schedbar() {
#if __has_builtin(__builtin_amdgcn_sched_barrier)
    __builtin_amdgcn_sched_barrier(0);
#endif
}
__device__ __forceinline__ f32x16 zf16() {
    f32x16 z;
#pragma unroll
    for (int i = 0; i < 16; ++i) z[i] = 0.f;
    return z;
}
__device__ __forceinline__ s16x8 zs8() {
    s16x8 z;
#pragma unroll
    for (int i = 0; i < 8; ++i) z[i] = 0;
    return z;
}

union U8 { s16x8 v; unsigned int u[4]; };

// ---------------- kernel 1: detect + weights->LDS + MLP -> Qb, Kb, Vt -------
// (r9/r10-validated, unchanged)
__global__ __launch_bounds__(256) void k1_qkv(
    const void* __restrict__ xmain, const void* __restrict__ xmod,
    const void* __restrict__ we1, const void* __restrict__ we2,
    const void* __restrict__ wqp, const void* __restrict__ wkp,
    const void* __restrict__ wvp,
    u16* __restrict__ qb, u16* __restrict__ kb, u16* __restrict__ vt)
{
    __shared__ float wf[4608];
    __shared__ int   sflag;
    __shared__ float lh1[64][4][17];
    __shared__ float lh2[64][17];

    const int t = threadIdx.x;
    const int r = t >> 2;
    const int p = t & 3;
    const int row = blockIdx.x * 64 + r;

    if (t == 0) sflag = 0;
    __syncthreads();
    {
        float v = bf2f(((const u16*)xmod)[2 * t]);
        if (fabsf(v) > 16.f) atomicAdd(&sflag, 1);
    }
    __syncthreads();
    const int isf32 = (sflag > 8);

    const float SCL = 0.51006979f;       // (1/sqrt(8)) * log2(e)
    if (isf32) {
        const float* a1 = (const float*)we1; const float* a2 = (const float*)we2;
        const float* aq = (const float*)wqp; const float* ak = (const float*)wkp;
        const float* av = (const float*)wvp;
        for (int i = t; i < 4608; i += 256) {
            if      (i < 3072) wf[i] = a1[i];
            else if (i < 3328) wf[i] = a2[i - 3072];
            else if (i < 3456) wf[i] = aq[i - 3328] * SCL;
            else if (i < 3584) wf[i] = ak[i - 3456];
            else               wf[i] = av[i - 3584];
        }
    } else {
        const u16* a1 = (const u16*)we1; const u16* a2 = (const u16*)we2;
        const u16* aq = (const u16*)wqp; const u16* ak = (const u16*)wkp;
        const u16* av = (const u16*)wvp;
        for (int i = t; i < 4608; i += 256) {
            if      (i < 3072) wf[i] = bf2f(a1[i]);
            else if (i < 3328) wf[i] = bf2f(a2[i - 3072]);
            else if (i < 3456) wf[i] = bf2f(aq[i - 3328]) * SCL;
            else if (i < 3584) wf[i] = bf2f(ak[i - 3456]);
            else               wf[i] = bf2f(av[i - 3584]);
        }
    }
    __syncthreads();

    const float* __restrict__ W1 = wf;
    const float* __restrict__ W2 = wf + 3072;
    const float* __restrict__ Wq = wf + 3328;
    const float* __restrict__ Wk = wf + 3456;
    const float* __restrict__ Wv = wf + 3584;

    float h1p[16];
#pragma unroll
    for (int o = 0; o < 16; ++o) h1p[o] = 0.f;

    if (isf32) {
#pragma unroll
        for (int cc = 0; cc < 12; ++cc) {
            const int c = p + cc * 4;
            float4 xv = (c < 16)
                ? ((const float4*)xmain)[(size_t)row * 16 + c]
                : ((const float4*)xmod)[(size_t)row * 32 + (c - 16)];
            float xs[4] = {xv.x, xv.y, xv.z, xv.w};
#pragma unroll
            for (int j = 0; j < 4; ++j) {
                const float* wr = W1 + (c * 4 + j) * 16;
#pragma unroll
                for (int o = 0; o < 16; ++o) h1p[o] += xs[j] * wr[o];
            }
        }
    } else {
#pragma unroll
        for (int cc = 0; cc < 12; ++cc) {
            const int c = p + cc * 4;
            uint2 xv = (c < 16)
                ? ((const uint2*)xmain)[(size_t)row * 16 + c]
                : ((const uint2*)xmod)[(size_t)row * 32 + (c - 16)];
            float xs[4] = { bf2f((u16)(xv.x & 0xffff)), bf2f((u16)(xv.x >> 16)),
                            bf2f((u16)(xv.y & 0xffff)), bf2f((u16)(xv.y >> 16)) };
#pragma unroll
            for (int j = 0; j < 4; ++j) {
                const float* wr = W1 + (c * 4 + j) * 16;
#pragma unroll
                for (int o = 0; o < 16; ++o) h1p[o] += xs[j] * wr[o];
            }
        }
    }
#pragma unroll
    for (int o = 0; o < 16; ++o) lh1[r][p][o] = h1p[o];
    __syncthreads();

    float h1[16];
#pragma unroll
    for (int o = 0; o < 16; ++o)
        h1[o] = fmaxf(lh1[r][0][o] + lh1[r][1][o] + lh1[r][2][o] + lh1[r][3][o], 0.f);

#pragma unroll
    for (int oo = 0; oo < 4; ++oo) {
        const int o = p * 4 + oo;
        float s = 0.f;
#pragma unroll
        for (int j = 0; j < 16; ++j) s += h1[j] * W2[j * 16 + o];
        lh2[r][o] = fmaxf(s, 0.f);
    }
    __syncthreads();

    float h2[16];
#pragma unroll
    for (int j = 0; j < 16; ++j) h2[j] = lh2[r][j];

    {
        float q0 = 0.f, q1 = 0.f, k0 = 0.f, k1 = 0.f;
        const int o = 2 * p;
#pragma unroll
        for (int j = 0; j < 16; ++j) {
            q0 += h2[j] * Wq[j * 8 + o];
            q1 += h2[j] * Wq[j * 8 + o + 1];
            k0 += h2[j] * Wk[j * 8 + o];
            k1 += h2[j] * Wk[j * 8 + o + 1];
        }
        ((unsigned int*)qb)[(size_t)row * 4 + p] = pk2(q0, q1);
        ((unsigned int*)kb)[(size_t)row * 4 + p] = pk2(k0, k1);
    }

    // V store, key-tiled layout: [tile][c][kk], row stride 36 u16 (72 B)
    const int tI = row >> 5, kk = row & 31;
#pragma unroll
    for (int c16 = 0; c16 < 16; ++c16) {
        const int c = p * 16 + c16;
        float v = 0.f;
#pragma unroll
        for (int j = 0; j < 16; ++j) v += h2[j] * Wv[j * 64 + c];
        vt[(size_t)tI * 2304 + c * 36 + kk] = f2bf(v);
    }
}

// --------------------------- kernel 2: attention partials -------------------
// grid = 96 q-blocks * S key-splits; block = 128 queries (4 waves x 32q);
// all waves sweep the same keys through a 3-DEEP shared V-tile buffer.
// AITER-style pipeline: s_waitcnt vmcnt(2) (tile kt+1's DMAs stay in
// flight) + raw s_barrier per iteration; vmcnt(0) only on last two iters.
__global__ __launch_bounds__(256, 6) void k2_attn(
    const u16* __restrict__ qb, const u16* __restrict__ kb,
    const u16* __restrict__ vt,
    u16* __restrict__ po, float* __restrict__ pl,
    int nsplit, int tiles)
{
    __shared__ union SM {
        uint4 stage[3][288];                 // 13824 B, 3-deep V-tile ring
        float sf[2304];                      // epilogue transpose (aliased)
    } sm;

    const int tid  = threadIdx.x;
    const int lane = tid & 63;
    const int half = lane >> 5;
    const int l31  = lane & 31;
    const int w    = tid >> 6;               // wave 0..3
    const int qB   = (blockIdx.x % 96) * 128;
    const int sp   = blockIdx.x / 96;
    const int myq  = qB + 32 * w;
    const int key_start = sp * (NN / nsplit);
    const int t0 = key_start >> 5;

    const f32x16 Z = zf16();
    s16x8 qf = zs8();
    if (!half) qf = *(const s16x8*)(qb + (size_t)(myq + l31) * 8);

    f32x16 acc0 = Z, acc1 = Z;
    float ls = 0.f;

    const char* gvt = (const char*)vt;
    // wave w stages its quarter (1152 B) of tile tt into ring buffer b
#define STAGE_TILE(tt, b)                                                     \
    do {                                                                      \
        const char* g_ = gvt + (size_t)(t0 + (tt)) * 4608 + 1152 * w + lane * 16; \
        char* l_ = (char*)&sm.stage[(b)][0] + 1152 * w;                       \
        gld16(g_, l_);                                                        \
        if (lane < 8) gld16(g_ + 1024, l_ + 1024);                            \
    } while (0)

    // prologue: DMA(0), K(0), DMA(1)  -> vmcnt order matters
    STAGE_TILE(0, 0);
    s16x8 ka_c = *(const s16x8*)(kb + (size_t)(key_start + l31) * 8);
    if (tiles > 1) STAGE_TILE(1, 1);

    for (int kt = 0; kt < tiles; ++kt) {
        // wait own tile-kt DMAs + K(kt); leave tile-(kt+1) DMAs in flight
        if (kt + 2 < tiles) __builtin_amdgcn_s_waitcnt(0x0F72);  // vmcnt(2)
        else                __builtin_amdgcn_s_waitcnt(0x0F70);  // vmcnt(0)
        __builtin_amdgcn_s_barrier();        // raw: no compiler drain
        schedbar();                          // keep ds_reads below barrier
        const int cb = kt % 3;

        s16x8 ka_n;
        if (kt + 1 < tiles)
            ka_n = *(const s16x8*)(kb + (size_t)(key_start + (kt + 1) * 32 + l31) * 8);
        if (kt + 2 < tiles)
            STAGE_TILE(kt + 2, (kt + 2) % 3);

        // S^T = K.Q^T (Q half1 zero -> one-sided qk pad)
        f32x16 S = MFMA_32x32x16_BF16(ka_c, qf, Z, 0, 0, 0);

        float pr[16];
        float ls0 = 0.f, ls1 = 0.f;
#pragma unroll
        for (int r = 0; r < 8; ++r) {
            pr[r]     = __builtin_amdgcn_exp2f(S[r]);
            pr[r + 8] = __builtin_amdgcn_exp2f(S[r + 8]);
            ls0 += pr[r];
            ls1 += pr[r + 8];
        }
        ls += ls0 + ls1;

        U8 pb0, pb1;
#pragma unroll
        for (int i = 0; i < 4; ++i) {
            pb0.u[i] = pkbf(pr[2 * i],     pr[2 * i + 1]);
            pb1.u[i] = pkbf(pr[8 + 2 * i], pr[8 + 2 * i + 1]);
        }

        // A-fragments from the shared LDS tile (r5-validated relabeling)
        const u16* base = (const u16*)&sm.stage[cb][0];
        const u16* r0 = base + l31 * 36 + 4 * half;          // ct=0
        const u16* r1 = base + (32 + l31) * 36 + 4 * half;   // ct=1
        U8 va;
        uint2 x0, x1;
        x0 = *(const uint2*)(r0);       x1 = *(const uint2*)(r0 + 8);
        va.u[0] = x0.x; va.u[1] = x0.y; va.u[2] = x1.x; va.u[3] = x1.y;
        acc0 = MFMA_32x32x16_BF16(va.v, pb0.v, acc0, 0, 0, 0);
        x0 = *(const uint2*)(r1);       x1 = *(const uint2*)(r1 + 8);
        va.u[0] = x0.x; va.u[1] = x0.y; va.u[2] = x1.x; va.u[3] = x1.y;
        acc1 = MFMA_32x32x16_BF16(va.v, pb0.v, acc1, 0, 0, 0);
        x0 = *(const uint2*)(r0 + 16);  x1 = *(const uint2*)(r0 + 24);
        va.u[0] = x0.x; va.u[1] = x0.y; va.u[2] = x1.x; va.u[3] = x1.y;
        acc0 = MFMA_32x32x16_BF16(va.v, pb1.v, acc0, 0, 0, 0);
        x0 = *(const uint2*)(r1 + 16);  x1 = *(const uint2*)(r1 + 24);
        va.u[0] = x0.x; va.u[1] = x0.y; va.u[2] = x1.x; va.u[3] = x1.y;
        acc1 = MFMA_32x32x16_BF16(va.v, pb1.v, acc1, 0, 0, 0);

        if (kt + 1 < tiles) ka_c = ka_n;
    }
#undef STAGE_TILE

    // lanes l and l+32 hold complementary key-halves of query l31's sum
    ls += __shfl_xor(ls, 32, 64);

    // ---- epilogue: per-wave transpose through the (aliased) staging LDS ----
    u16* poS = po + (size_t)sp * (NN * 64);
    for (int j = 0; j < 4; ++j) {
        __syncthreads();
        if (w == j) {
#pragma unroll
            for (int r = 0; r < 16; ++r) {
                const int c = (r & 3) + 8 * (r >> 2) + 4 * half;
                sm.sf[c * 33 + l31]        = acc0[r];
                sm.sf[(32 + c) * 33 + l31] = acc1[r];
            }
            if (lane < 32) sm.sf[2112 + l31] = ls;
        }
        __syncthreads();
        const int rq = tid >> 3;             // query 0..31
        const int c0 = (tid & 7) * 8;        // channel base
        unsigned int u0 = pkbf(sm.sf[(c0 + 0) * 33 + rq], sm.sf[(c0 + 1) * 33 + rq]);
        unsigned int u1 = pkbf(sm.sf[(c0 + 2) * 33 + rq], sm.sf[(c0 + 3) * 33 + rq]);
        unsigned int u2 = pkbf(sm.sf[(c0 + 4) * 33 + rq], sm.sf[(c0 + 5) * 33 + rq]);
        unsigned int u3 = pkbf(sm.sf[(c0 + 6) * 33 + rq], sm.sf[(c0 + 7) * 33 + rq]);
        *(uint4*)(poS + (size_t)(qB + 32 * j + rq) * 64 + c0) =
            make_uint4(u0, u1, u2, u3);
        if (tid < 32)
            pl[(size_t)sp * NN + qB + 32 * j + tid] = sm.sf[2112 + tid];
    }
}

// --------------------------- kernel 3: reduce splits + normalize ------------
__global__ __launch_bounds__(256) void k3_norm(
    const u16* __restrict__ po, const float* __restrict__ pl,
    float4* __restrict__ out, int nsplit)
{
    const int i = blockIdx.x * 256 + threadIdx.x;   // 196608 float4 outputs
    const int row = i >> 4;
    const int c0 = (i & 15) * 4;
    float l = 0.f;
    float o0 = 0.f, o1 = 0.f, o2 = 0.f, o3 = 0.f;
    for (int s = 0; s < nsplit; ++s) {
        l += pl[(size_t)s * NN + row];
        uint2 p = *(const uint2*)(po + (size_t)s * (NN * 64) +
                                  (size_t)row * 64 + c0);
        o0 += bf2f((u16)(p.x & 0xffff)); o1 += bf2f((u16)(p.x >> 16));
        o2 += bf2f((u16)(p.y & 0xffff)); o3 += bf2f((u16)(p.y >> 16));
    }
    const float rl = 1.0f / l;
    out[i] = make_float4(o0 * rl, o1 * rl, o2 * rl, o3 * rl);
}

// ---------------------------------------------------------------------------
extern "C" void kernel_launch(void* const* d_in, const int* in_sizes, int n_in,
                              void* d_out, int out_size, void* d_ws, size_t ws_size,
                              hipStream_t stream)
{
    const void* xmain = d_in[0];
    const void* xmod  = d_in[1];
    // d_in[2] = xyz (unused by the reference)
    const void* we1   = d_in[3];
    const void* we2   = d_in[4];
    const void* wq    = d_in[5];
    const void* wk    = d_in[6];
    const void* wv    = d_in[7];

    char* ws = (char*)d_ws;
    u16*   qb   = (u16*)  (ws + OFF_QB);
    u16*   kb   = (u16*)  (ws + OFF_KB);
    u16*   vt   = (u16*)  (ws + OFF_VT);

    // pick the largest key-split S whose partials fit in ws
    int S = 1;
    for (int cand = 16; cand >= 1; cand >>= 1) {
        size_t need = (size_t)OFF_PO + (size_t)cand * (NN * 64 * 2) +
                      (size_t)cand * (NN * 4);
        if (ws_size >= need) { S = cand; break; }
    }
    u16*   po = (u16*)(ws + OFF_PO);
    float* pl = (float*)(ws + OFF_PO + (size_t)S * (NN * 64 * 2));
    const int tiles = NN / (32 * S);

    k1_qkv<<<192, 256, 0, stream>>>(xmain, xmod, we1, we2, wq, wk, wv,
                                    qb, kb, vt);
    k2_attn<<<96 * S, 256, 0, stream>>>(qb, kb, vt, po, pl, S, tiles);
    k3_norm<<<768, 256, 0, stream>>>(po, pl, (float4*)d_out, S);
}